// Round 4
// baseline (343.939 us; speedup 1.0000x reference)
//
#include <hip/hip_runtime.h>
#include <hip/hip_bf16.h>
#include <math.h>

#define B_    4
#define CIN_  64
#define COUT_ 64
#define H_    128
#define W_    160
#define HW_   (H_*W_)
#define NPIX_ (B_*HW_)      // 81920
#define XC_   72            // NHWC channel stride: x(64) + sim(8)
#define OMC_  28            // om channels padded (27 used)
#define EPS_  1e-8f

typedef float  f4    __attribute__((ext_vector_type(4)));
typedef float  f32x4 __attribute__((ext_vector_type(4)));
typedef short  bf16x8 __attribute__((ext_vector_type(8)));
typedef unsigned short ushort_t;

static __device__ __forceinline__ short f2bf_s(float f) {
    __hip_bfloat16 h = __float2bfloat16(f);
    return *reinterpret_cast<short*>(&h);
}

// ---------------------------------------------------------------------------
// prep:
//  wstage[k][g] bf16 (9*4096): pre-transposed + pre-SWIZZLED dcn weights so a
//    LINEAR 16B copy into LDS yields Wt[o][c] with byte ^= ((o&7)<<4).
//  cwT[c][t][o28] f32: cm weights, padded to 28 couts (pad = 0).
// ---------------------------------------------------------------------------
__global__ __launch_bounds__(256) void prep_kernel(const float* __restrict__ wt,
                                                   const float* __restrict__ cmw,
                                                   short* __restrict__ wstage,
                                                   float* __restrict__ cwT)
{
    int i = blockIdx.x * 256 + threadIdx.x;
    if (i < 9*4096) {
        int k = i >> 12, g = i & 4095;
        int row = g >> 6;                                   // o
        int cc  = ((((g & 63) << 1) ^ ((row & 7) << 4)) >> 1);
        wstage[i] = f2bf_s(wt[(row*64 + cc)*9 + k]);
    }
    int j = i - 9*4096;
    if (j >= 0 && j < 72*9*28) {
        int c = j / 252, r = j % 252, t = r / 28, o = r % 28;
        cwT[j] = (o < 27) ? cmw[(o*72 + c)*9 + t] : 0.f;
    }
}

// ---------------------------------------------------------------------------
// xpose: NCHW x -> NHWC xs[px][0..63]  (channels 64..71 filled by sim_kernel)
// ---------------------------------------------------------------------------
__global__ __launch_bounds__(128) void xpose_kernel(const float* __restrict__ x,
                                                    float* __restrict__ xs)
{
    __shared__ float l[128][65];
    const int t = threadIdx.x;
    const int px0 = blockIdx.x * 128;
    const int b = px0 / HW_, p0 = px0 % HW_;
    for (int c = 0; c < 64; c++)
        l[t][c] = x[((size_t)(b*64 + c))*HW_ + p0 + t];
    __syncthreads();
#pragma unroll
    for (int rep = 0; rep < 16; rep++) {
        int pxl = (t >> 4) + rep*8;
        int c4  = (t & 15) * 4;
        f4 v = { l[pxl][c4], l[pxl][c4+1], l[pxl][c4+2], l[pxl][c4+3] };
        *reinterpret_cast<f4*>(&xs[(size_t)(px0+pxl)*XC_ + c4]) = v;
    }
}

// ---------------------------------------------------------------------------
// sim: 2 threads/pixel (channel halves), shfl_xor(1) combine. Grid 640.
// ---------------------------------------------------------------------------
__global__ __launch_bounds__(256, 2) void sim_kernel(float* __restrict__ xs)
{
    const int t = threadIdx.x;
    const int wg = blockIdx.x;
    const int sw = (wg & 7) * 80 + (wg >> 3);               // XCD-contiguous
    const int px = sw * 128 + (t >> 1);
    const int h = t & 1;
    const int w = px % W_, hh = (px / W_) % H_, b = px / HW_;

    const float* cen = xs + (size_t)px * XC_ + h*32;
    f4 cv[8]; float ncc = 0.f;
#pragma unroll
    for (int q = 0; q < 8; q++) {
        cv[q] = *reinterpret_cast<const f4*>(cen + q*4);
#pragma unroll
        for (int j = 0; j < 4; j++) ncc = fmaf(cv[q][j], cv[q][j], ncc);
    }

    const int kyA[8] = {-1,-1,-1, 0, 0, 1, 1, 1};
    const int kxA[8] = {-1, 0, 1,-1, 1,-1, 0, 1};
    float dot[8], nn[8];
#pragma unroll
    for (int n = 0; n < 8; n++) {
        int hn = hh + kyA[n], wn = w + kxA[n];
        bool v = (hn >= 0) & (hn < H_) & (wn >= 0) & (wn < W_);
        float msk = v ? 1.f : 0.f;
        const float* nb = xs + (size_t)(b*HW_ + min(max(hn,0),H_-1)*W_ + min(max(wn,0),W_-1))*XC_ + h*32;
        float d = 0.f, s2 = 0.f;
#pragma unroll
        for (int q = 0; q < 8; q++) {
            f4 qv = *reinterpret_cast<const f4*>(nb + q*4);
#pragma unroll
            for (int j = 0; j < 4; j++) {
                float vv = qv[j] * msk;
                d  = fmaf(cv[q][j], vv, d);
                s2 = fmaf(vv, vv, s2);
            }
        }
        dot[n] = d; nn[n] = s2;
    }
    ncc += __shfl_xor(ncc, 1);
    const float ncr = 1.f / fmaxf(sqrtf(ncc), EPS_);
    float res[8];
#pragma unroll
    for (int n = 0; n < 8; n++) {
        float dt = dot[n] + __shfl_xor(dot[n], 1);
        float s2 = nn[n]  + __shfl_xor(nn[n], 1);
        res[n] = dt * ncr / fmaxf(sqrtf(s2), EPS_);
    }
    f4 r = { h ? res[4] : res[0], h ? res[5] : res[1],
             h ? res[6] : res[2], h ? res[7] : res[3] };
    *reinterpret_cast<f4*>(xs + (size_t)px * XC_ + 64 + h*4) = r;
}

// ---------------------------------------------------------------------------
// cm: 3x3 conv 72->27(+pad). Wave-pair K-split (h = wv>>1 is wave-uniform so
// weight addrs stay SGPR). LDS reduce. Grid 640. om NHWC [px][28].
// ---------------------------------------------------------------------------
__global__ __launch_bounds__(256, 2) void cm_kernel(const float* __restrict__ xs,
                                                    const float* __restrict__ cwT,
                                                    const float* __restrict__ cmb,
                                                    float* __restrict__ om)
{
    __shared__ float red[128][29];                          // stride 29: conflict-free
    const int t = threadIdx.x;
    const int wg = blockIdx.x;
    const int sw = (wg & 7) * 80 + (wg >> 3);
    const int wv = t >> 6, lane = t & 63;
    const int h  = wv >> 1;                                 // K-half, wave-uniform
    const int pxl = (wv & 1) * 64 + lane;
    const int px = sw * 128 + pxl;
    const int w = px % W_, hh = (px / W_) % H_, b = px / HW_;
    const int c0 = h * 36;

    float acc[28];
#pragma unroll
    for (int o = 0; o < 28; o++) acc[o] = 0.f;

#pragma unroll 1
    for (int t9 = 0; t9 < 9; t9++) {
        int hy = hh + t9/3 - 1, wx = w + t9%3 - 1;
        bool vld = (hy >= 0) & (hy < H_) & (wx >= 0) & (wx < W_);
        float msk = vld ? 1.f : 0.f;
        const float* nb = xs + (size_t)(b*HW_ + min(max(hy,0),H_-1)*W_ + min(max(wx,0),W_-1))*XC_ + c0;
#pragma unroll
        for (int c4 = 0; c4 < 9; c4++) {
            f4 xv = *reinterpret_cast<const f4*>(nb + c4*4);
#pragma unroll
            for (int j = 0; j < 4; j++) {
                float v = xv[j] * msk;
                const float* wr = &cwT[(size_t)((c0 + c4*4 + j)*9 + t9)*28];
#pragma unroll
                for (int o = 0; o < 28; o++) acc[o] = fmaf(v, wr[o], acc[o]);
            }
        }
    }

    if (h == 0) {
#pragma unroll
        for (int o = 0; o < 28; o++) red[pxl][o] = acc[o];
    }
    __syncthreads();
    if (h == 1) {
        float sum[28];
#pragma unroll
        for (int o = 0; o < 27; o++) sum[o] = acc[o] + red[pxl][o] + cmb[o];
        sum[27] = 0.f;
        float* op = om + (size_t)px * OMC_;
#pragma unroll
        for (int q = 0; q < 7; q++) {
            f4 r = { sum[q*4], sum[q*4+1], sum[q*4+2], sum[q*4+3] };
            *reinterpret_cast<f4*>(op + q*4) = r;
        }
    }
}

// ---------------------------------------------------------------------------
// dcn: bf16 MFMA implicit GEMM, latency-tolerant. Block = 64 px x 64 o,
// 4 waves (16px x 64o each). 4 threads/px gather 16 ch each (16 loads in
// flight = 64 VGPR). om(k+1) + W(k) prefetched before the gather-wait.
// ---------------------------------------------------------------------------
__global__ __launch_bounds__(256, 2) void dcn_kernel(const float* __restrict__ xs,
                                                     const float* __restrict__ om,
                                                     const short* __restrict__ wstage,
                                                     const float* __restrict__ bias,
                                                     float* __restrict__ out)
{
    __shared__ __align__(16) short As[64*64];               // 8 KB, row=px (128B)
    __shared__ __align__(16) short Ws[64*64];               // 8 KB, row=o  (128B)

    const int t  = threadIdx.x;
    const int wg = blockIdx.x;
    const int sw = (wg & 7) * 160 + (wg >> 3);              // XCD-contiguous
    const int px0 = sw * 64;

    const int lane = t & 63, wv = t >> 6;
    const int fr = lane & 15, fq = lane >> 4;
    const int swz = (fr & 7) << 4;

    const int pxl = t >> 2, q4 = t & 3;                     // pixel, ch-quarter
    const int pxs = px0 + pxl;
    const int wsx = pxs % W_, hs = (pxs / W_) % H_, bs = pxs / HW_;
    const float* omp = om + (size_t)pxs * OMC_;
    const size_t xrow = (size_t)bs * HW_;
    const int cb = q4 * 32;                                 // byte base of 16 ch

    f32x4 acc[4];
#pragma unroll
    for (int j = 0; j < 4; j++) acc[j] = (f32x4){0.f,0.f,0.f,0.f};

    float dy = omp[0], dx = omp[1], mz = omp[18];

#pragma unroll 1
    for (int k = 0; k < 9; k++) {
        float m  = 1.f / (1.f + __expf(-mz));
        float py = (float)(hs + k/3 - 1) + dy;
        float pxx= (float)(wsx + k%3 - 1) + dx;
        float y0f = floorf(py), x0f = floorf(pxx);
        int   y0 = (int)y0f,   x0 = (int)x0f;
        float wy = py - y0f,   wx = pxx - x0f;
        bool vy0 = (y0 >= 0)  & (y0 < H_);
        bool vy1 = (y0 >= -1) & (y0 < H_ - 1);
        bool vx0 = (x0 >= 0)  & (x0 < W_);
        bool vx1 = (x0 >= -1) & (x0 < W_ - 1);
        float w00 = (1.f-wy)*(1.f-wx)*m*((vy0&vx0)?1.f:0.f);
        float w01 = (1.f-wy)*wx      *m*((vy0&vx1)?1.f:0.f);
        float w10 = wy*(1.f-wx)      *m*((vy1&vx0)?1.f:0.f);
        float w11 = wy*wx            *m*((vy1&vx1)?1.f:0.f);
        int y0c = min(max(y0,   0), H_-1), y1c = min(max(y0+1, 0), H_-1);
        int x0c = min(max(x0,   0), W_-1), x1c = min(max(x0+1, 0), W_-1);
        const float* p00 = xs + (size_t)(xrow + y0c*W_ + x0c)*XC_ + q4*16;
        const float* p01 = xs + (size_t)(xrow + y0c*W_ + x1c)*XC_ + q4*16;
        const float* p10 = xs + (size_t)(xrow + y1c*W_ + x0c)*XC_ + q4*16;
        const float* p11 = xs + (size_t)(xrow + y1c*W_ + x1c)*XC_ + q4*16;

        // ---- issue the 16 gathers first (oldest in vmcnt order) ----
        f4 ga[4], gb[4], gc[4], gd[4];
#pragma unroll
        for (int q = 0; q < 4; q++) ga[q] = *reinterpret_cast<const f4*>(p00 + q*4);
#pragma unroll
        for (int q = 0; q < 4; q++) gb[q] = *reinterpret_cast<const f4*>(p01 + q*4);
#pragma unroll
        for (int q = 0; q < 4; q++) gc[q] = *reinterpret_cast<const f4*>(p10 + q*4);
#pragma unroll
        for (int q = 0; q < 4; q++) gd[q] = *reinterpret_cast<const f4*>(p11 + q*4);

        // ---- prefetch W tile chunk + next tap's om (newer, still in flight) ----
        const short* wsrc = wstage + k*4096 + t*16;
        bf16x8 wv0 = *reinterpret_cast<const bf16x8*>(wsrc);
        bf16x8 wv1 = *reinterpret_cast<const bf16x8*>(wsrc + 8);
        int kn = (k < 8) ? k + 1 : 8;
        float dyn = omp[2*kn], dxn = omp[2*kn + 1], mzn = omp[18 + kn];

        // ---- combine + cvt ----
        bf16x8 us0, us1;
#pragma unroll
        for (int q = 0; q < 4; q++) {
#pragma unroll
            for (int j = 0; j < 4; j++) {
                float v = w00*ga[q][j] + w01*gb[q][j] + w10*gc[q][j] + w11*gd[q][j];
                short s = f2bf_s(v);
                if (q < 2) us0[q*4 + j] = s; else us1[(q-2)*4 + j] = s;
            }
        }

        __syncthreads();                                    // prev MFMA reads done
        *reinterpret_cast<bf16x8*>((char*)As + pxl*128 + ((cb     ) ^ ((pxl&7)<<4))) = us0;
        *reinterpret_cast<bf16x8*>((char*)As + pxl*128 + ((cb + 16) ^ ((pxl&7)<<4))) = us1;
        *reinterpret_cast<bf16x8*>((char*)Ws + t*32)      = wv0;
        *reinterpret_cast<bf16x8*>((char*)Ws + t*32 + 16) = wv1;
        __syncthreads();

#pragma unroll
        for (int s = 0; s < 2; s++) {
            const int bc = (s*64 + fq*16) ^ swz;
            bf16x8 a = *reinterpret_cast<const bf16x8*>((char*)As + (wv*16 + fr)*128 + bc);
#pragma unroll
            for (int j = 0; j < 4; j++) {
                bf16x8 bj = *reinterpret_cast<const bf16x8*>((char*)Ws + (j*16 + fr)*128 + bc);
                acc[j] = __builtin_amdgcn_mfma_f32_16x16x32_bf16(a, bj, acc[j], 0, 0, 0);
            }
        }
        dy = dyn; dx = dxn; mz = mzn;
    }

    // ---- epilogue: row px = wv*16 + fq*4 + reg, col o = j*16 + fr ----
    const int bo = px0 / HW_, po = px0 % HW_;
#pragma unroll
    for (int j = 0; j < 4; j++) {
        int o = j*16 + fr;
        float bv = bias[o];
        f4 r = { acc[j][0] + bv, acc[j][1] + bv, acc[j][2] + bv, acc[j][3] + bv };
        *reinterpret_cast<f4*>(&out[((size_t)(bo*64 + o))*HW_ + po + wv*16 + fq*4]) = r;
    }
}

// ---------------------------------------------------------------------------
extern "C" void kernel_launch(void* const* d_in, const int* in_sizes, int n_in,
                              void* d_out, int out_size, void* d_ws, size_t ws_size,
                              hipStream_t stream)
{
    const float* x   = (const float*)d_in[0];
    const float* wt  = (const float*)d_in[1];
    const float* bs  = (const float*)d_in[2];
    const float* cmw = (const float*)d_in[3];
    const float* cmb = (const float*)d_in[4];
    float* out = (float*)d_out;

    float* xs     = (float*)d_ws;                           // NPIX_*72 f32
    float* om     = xs + (size_t)NPIX_ * XC_;               // NPIX_*28 f32
    short* wstage = (short*)(om + (size_t)NPIX_ * OMC_);    // 9*4096 bf16
    float* cwT    = (float*)(wstage + 9*4096);              // 72*9*28 f32

    prep_kernel <<<215, 256, 0, stream>>>(wt, cmw, wstage, cwT);
    xpose_kernel<<<NPIX_/128, 128, 0, stream>>>(x, xs);
    sim_kernel  <<<NPIX_/128, 256, 0, stream>>>(xs);
    cm_kernel   <<<NPIX_/128, 256, 0, stream>>>(xs, cwT, cmb, om);
    dcn_kernel  <<<NPIX_/64,  256, 0, stream>>>(xs, om, wstage, bs, out);
}

// Round 5
// 121.840 us; speedup vs baseline: 2.8229x; 2.8229x over previous
//
#include <hip/hip_runtime.h>
#include <hip/hip_bf16.h>
#include <math.h>

#define B_    4
#define CIN_  64
#define COUT_ 64
#define H_    128
#define W_    160
#define HW_   (H_*W_)
#define NPIX_ (B_*HW_)      // 81920
#define XC_   72            // NHWC channel stride: x(64) + sim(8)
#define OMC_  28            // om channels padded (27 used)
#define EPS_  1e-8f
#define NCH_  21            // cm K-chunks: ceil(648/32)

typedef float  f4    __attribute__((ext_vector_type(4)));
typedef float  f32x4 __attribute__((ext_vector_type(4)));
typedef short  bf16x8 __attribute__((ext_vector_type(8)));
typedef short  s4v   __attribute__((ext_vector_type(4)));

static __device__ __forceinline__ short f2bf_s(float f) {
    __hip_bfloat16 h = __float2bfloat16(f);
    return *reinterpret_cast<short*>(&h);
}

// ---------------------------------------------------------------------------
// prep:
//  wstage[k][g] bf16 (9*4096): dcn weights pre-transposed + pre-SWIZZLED so a
//    LINEAR 16B copy into LDS yields Wt[o][c] with byte ^= ((o&7)<<4).
//  cwB[ch][o][kk] bf16 (21*32*32): cm weights per K-chunk, zero-padded
//    (o>=27 or k>=648). k = tap*72 + ch_in.
// ---------------------------------------------------------------------------
__global__ __launch_bounds__(256) void prep_kernel(const float* __restrict__ wt,
                                                   const float* __restrict__ cmw,
                                                   short* __restrict__ wstage,
                                                   short* __restrict__ cwB)
{
    int i = blockIdx.x * 256 + threadIdx.x;
    if (i < 9*4096) {
        int k = i >> 12, g = i & 4095;
        int row = g >> 6;                                   // o
        int cc  = ((((g & 63) << 1) ^ ((row & 7) << 4)) >> 1);
        wstage[i] = f2bf_s(wt[(row*64 + cc)*9 + k]);
    }
    int j = i - 9*4096;
    if (j >= 0 && j < NCH_*32*32) {
        int c  = j >> 10;                                   // chunk
        int r  = j & 1023;
        int o  = r >> 5, kk = r & 31;
        int k  = c*32 + kk;
        short v = 0;
        if (o < 27 && k < 648) {
            int tap = k / 72, ch = k - (k/72)*72;
            v = f2bf_s(cmw[((size_t)o*72 + ch)*9 + tap]);
        }
        cwB[j] = v;
    }
}

// ---------------------------------------------------------------------------
// xpose: NCHW x -> NHWC xs[px][0..63]  (channels 64..71 filled by sim_kernel)
// ---------------------------------------------------------------------------
__global__ __launch_bounds__(128) void xpose_kernel(const float* __restrict__ x,
                                                    float* __restrict__ xs)
{
    __shared__ float l[128][65];
    const int t = threadIdx.x;
    const int px0 = blockIdx.x * 128;
    const int b = px0 / HW_, p0 = px0 % HW_;
    for (int c = 0; c < 64; c++)
        l[t][c] = x[((size_t)(b*64 + c))*HW_ + p0 + t];
    __syncthreads();
#pragma unroll
    for (int rep = 0; rep < 16; rep++) {
        int pxl = (t >> 4) + rep*8;
        int c4  = (t & 15) * 4;
        f4 v = { l[pxl][c4], l[pxl][c4+1], l[pxl][c4+2], l[pxl][c4+3] };
        *reinterpret_cast<f4*>(&xs[(size_t)(px0+pxl)*XC_ + c4]) = v;
    }
}

// ---------------------------------------------------------------------------
// sim: 2 threads/pixel (channel halves), shfl_xor(1) combine. Grid 640.
// ---------------------------------------------------------------------------
__global__ __launch_bounds__(256, 2) void sim_kernel(float* __restrict__ xs)
{
    const int t = threadIdx.x;
    const int wg = blockIdx.x;
    const int sw = (wg & 7) * 80 + (wg >> 3);               // XCD-contiguous
    const int px = sw * 128 + (t >> 1);
    const int h = t & 1;
    const int w = px % W_, hh = (px / W_) % H_, b = px / HW_;

    const float* cen = xs + (size_t)px * XC_ + h*32;
    f4 cv[8]; float ncc = 0.f;
#pragma unroll
    for (int q = 0; q < 8; q++) {
        cv[q] = *reinterpret_cast<const f4*>(cen + q*4);
#pragma unroll
        for (int j = 0; j < 4; j++) ncc = fmaf(cv[q][j], cv[q][j], ncc);
    }

    const int kyA[8] = {-1,-1,-1, 0, 0, 1, 1, 1};
    const int kxA[8] = {-1, 0, 1,-1, 1,-1, 0, 1};
    float dot[8], nn[8];
#pragma unroll
    for (int n = 0; n < 8; n++) {
        int hn = hh + kyA[n], wn = w + kxA[n];
        bool v = (hn >= 0) & (hn < H_) & (wn >= 0) & (wn < W_);
        float msk = v ? 1.f : 0.f;
        const float* nb = xs + (size_t)(b*HW_ + min(max(hn,0),H_-1)*W_ + min(max(wn,0),W_-1))*XC_ + h*32;
        float d = 0.f, s2 = 0.f;
#pragma unroll
        for (int q = 0; q < 8; q++) {
            f4 qv = *reinterpret_cast<const f4*>(nb + q*4);
#pragma unroll
            for (int j = 0; j < 4; j++) {
                float vv = qv[j] * msk;
                d  = fmaf(cv[q][j], vv, d);
                s2 = fmaf(vv, vv, s2);
            }
        }
        dot[n] = d; nn[n] = s2;
    }
    ncc += __shfl_xor(ncc, 1);
    const float ncr = 1.f / fmaxf(sqrtf(ncc), EPS_);
    float res[8];
#pragma unroll
    for (int n = 0; n < 8; n++) {
        float dt = dot[n] + __shfl_xor(dot[n], 1);
        float s2 = nn[n]  + __shfl_xor(nn[n], 1);
        res[n] = dt * ncr / fmaxf(sqrtf(s2), EPS_);
    }
    f4 r = { h ? res[4] : res[0], h ? res[5] : res[1],
             h ? res[6] : res[2], h ? res[7] : res[3] };
    *reinterpret_cast<f4*>(xs + (size_t)px * XC_ + 64 + h*4) = r;
}

// ---------------------------------------------------------------------------
// cm: 3x3 conv 72->27 as bf16 MFMA implicit GEMM (same structure as dcn).
// Block = 64 px x 32 o, 4 waves (16px x 32o each). K = 648 padded to 21x32.
// Per chunk: each thread loads 8 k-values (one tap, 8 ch; never crosses a
// tap since 72%8==0), stages A[64px][32k] bf16 (80B stride) + W chunk, then
// 2 mfma/wave. Tap offsets/masks precomputed in an LDS table.
// ---------------------------------------------------------------------------
__global__ __launch_bounds__(256, 2) void cm_kernel(const float* __restrict__ xs,
                                                    const short* __restrict__ cwB,
                                                    const float* __restrict__ cmb,
                                                    float* __restrict__ om)
{
    __shared__ int   offs_l[64][10];
    __shared__ float msks_l[64][10];
    __shared__ __align__(16) char As[64*80];                // [px][32k] bf16, 80B stride
    __shared__ __align__(16) char Wsl[32*80];               // [o][32k]  bf16, 80B stride

    const int t  = threadIdx.x;
    const int wg = blockIdx.x;
    const int sw = (wg & 7) * 160 + (wg >> 3);              // XCD-contiguous
    const int px0 = sw * 64;

    const int lane = t & 63, wv = t >> 6;
    const int fr = lane & 15, fq = lane >> 4;
    const int pxl = t >> 2, q4 = t & 3;

    // ---- per-pixel tap offset/mask table ----
    for (int i = t; i < 576; i += 256) {
        int pxi = i / 9, tap = i - (i/9)*9;
        int p = px0 + pxi;
        int wp = p % W_, hp = (p / W_) % H_, bp = p / HW_;
        int hy = hp + tap/3 - 1, wx = wp + tap%3 - 1;
        bool vld = (hy >= 0) & (hy < H_) & (wx >= 0) & (wx < W_);
        offs_l[pxi][tap] = bp*HW_ + min(max(hy,0),H_-1)*W_ + min(max(wx,0),W_-1);
        msks_l[pxi][tap] = vld ? 1.f : 0.f;
    }
    __syncthreads();

    f32x4 acc[2];
    acc[0] = (f32x4){0.f,0.f,0.f,0.f};
    acc[1] = (f32x4){0.f,0.f,0.f,0.f};

#pragma unroll 1
    for (int chunk = 0; chunk < NCH_; chunk++) {
        int kb  = chunk*32 + q4*8;
        int tap = (kb * 911) >> 16;                         // floor(kb/72), verified
        tap = min(tap, 8);
        int ch  = kb - tap*72;
        float valid = (kb < 648) ? 1.f : 0.f;
        int   off = offs_l[pxl][tap];
        float msk = msks_l[pxl][tap] * valid;
        const float* src = xs + (size_t)off * XC_ + ch;

        f4 g0 = *reinterpret_cast<const f4*>(src);
        f4 g1 = *reinterpret_cast<const f4*>(src + 4);
        s4v wv4 = *reinterpret_cast<const s4v*>(cwB + chunk*1024 + t*4);

        bf16x8 us;
#pragma unroll
        for (int j = 0; j < 4; j++) us[j]     = f2bf_s(g0[j] * msk);
#pragma unroll
        for (int j = 0; j < 4; j++) us[4 + j] = f2bf_s(g1[j] * msk);

        __syncthreads();                                    // prev MFMA reads done
        *reinterpret_cast<bf16x8*>(As + pxl*80 + q4*16) = us;
        *reinterpret_cast<s4v*>(Wsl + (t >> 3)*80 + (t & 7)*8) = wv4;
        __syncthreads();

        bf16x8 a  = *reinterpret_cast<const bf16x8*>(As  + (wv*16 + fr)*80 + fq*16);
        bf16x8 b0 = *reinterpret_cast<const bf16x8*>(Wsl + (      fr)*80 + fq*16);
        bf16x8 b1 = *reinterpret_cast<const bf16x8*>(Wsl + (16 +  fr)*80 + fq*16);
        acc[0] = __builtin_amdgcn_mfma_f32_16x16x32_bf16(a, b0, acc[0], 0, 0, 0);
        acc[1] = __builtin_amdgcn_mfma_f32_16x16x32_bf16(a, b1, acc[1], 0, 0, 0);
    }

    // ---- epilogue: row px = wv*16 + fq*4 + reg, col o = j*16 + fr ----
    const int pxr = px0 + wv*16 + fq*4;
#pragma unroll
    for (int j = 0; j < 2; j++) {
        int o = j*16 + fr;
        if (o < 27) {
            float bv = cmb[o];
#pragma unroll
            for (int r = 0; r < 4; r++)
                om[(size_t)(pxr + r) * OMC_ + o] = acc[j][r] + bv;
        }
    }
}

// ---------------------------------------------------------------------------
// dcn: bf16 MFMA implicit GEMM, latency-tolerant. Block = 64 px x 64 o,
// 4 waves (16px x 64o each). 4 threads/px gather 16 ch each; om(k+1) + W(k)
// prefetched before the gather-wait.
// ---------------------------------------------------------------------------
__global__ __launch_bounds__(256, 2) void dcn_kernel(const float* __restrict__ xs,
                                                     const float* __restrict__ om,
                                                     const short* __restrict__ wstage,
                                                     const float* __restrict__ bias,
                                                     float* __restrict__ out)
{
    __shared__ __align__(16) short As[64*64];               // 8 KB, row=px (128B)
    __shared__ __align__(16) short Ws[64*64];               // 8 KB, row=o  (128B)

    const int t  = threadIdx.x;
    const int wg = blockIdx.x;
    const int sw = (wg & 7) * 160 + (wg >> 3);              // XCD-contiguous
    const int px0 = sw * 64;

    const int lane = t & 63, wv = t >> 6;
    const int fr = lane & 15, fq = lane >> 4;
    const int swz = (fr & 7) << 4;

    const int pxl = t >> 2, q4 = t & 3;                     // pixel, ch-quarter
    const int pxs = px0 + pxl;
    const int wsx = pxs % W_, hs = (pxs / W_) % H_, bs = pxs / HW_;
    const float* omp = om + (size_t)pxs * OMC_;
    const size_t xrow = (size_t)bs * HW_;
    const int cb = q4 * 32;                                 // byte base of 16 ch

    f32x4 acc[4];
#pragma unroll
    for (int j = 0; j < 4; j++) acc[j] = (f32x4){0.f,0.f,0.f,0.f};

    float dy = omp[0], dx = omp[1], mz = omp[18];

#pragma unroll 1
    for (int k = 0; k < 9; k++) {
        float m  = 1.f / (1.f + __expf(-mz));
        float py = (float)(hs + k/3 - 1) + dy;
        float pxx= (float)(wsx + k%3 - 1) + dx;
        float y0f = floorf(py), x0f = floorf(pxx);
        int   y0 = (int)y0f,   x0 = (int)x0f;
        float wy = py - y0f,   wx = pxx - x0f;
        bool vy0 = (y0 >= 0)  & (y0 < H_);
        bool vy1 = (y0 >= -1) & (y0 < H_ - 1);
        bool vx0 = (x0 >= 0)  & (x0 < W_);
        bool vx1 = (x0 >= -1) & (x0 < W_ - 1);
        float w00 = (1.f-wy)*(1.f-wx)*m*((vy0&vx0)?1.f:0.f);
        float w01 = (1.f-wy)*wx      *m*((vy0&vx1)?1.f:0.f);
        float w10 = wy*(1.f-wx)      *m*((vy1&vx0)?1.f:0.f);
        float w11 = wy*wx            *m*((vy1&vx1)?1.f:0.f);
        int y0c = min(max(y0,   0), H_-1), y1c = min(max(y0+1, 0), H_-1);
        int x0c = min(max(x0,   0), W_-1), x1c = min(max(x0+1, 0), W_-1);
        const float* p00 = xs + (size_t)(xrow + y0c*W_ + x0c)*XC_ + q4*16;
        const float* p01 = xs + (size_t)(xrow + y0c*W_ + x1c)*XC_ + q4*16;
        const float* p10 = xs + (size_t)(xrow + y1c*W_ + x0c)*XC_ + q4*16;
        const float* p11 = xs + (size_t)(xrow + y1c*W_ + x1c)*XC_ + q4*16;

        // ---- issue the 16 gathers first (oldest in vmcnt order) ----
        f4 ga[4], gb[4], gc[4], gd[4];
#pragma unroll
        for (int q = 0; q < 4; q++) ga[q] = *reinterpret_cast<const f4*>(p00 + q*4);
#pragma unroll
        for (int q = 0; q < 4; q++) gb[q] = *reinterpret_cast<const f4*>(p01 + q*4);
#pragma unroll
        for (int q = 0; q < 4; q++) gc[q] = *reinterpret_cast<const f4*>(p10 + q*4);
#pragma unroll
        for (int q = 0; q < 4; q++) gd[q] = *reinterpret_cast<const f4*>(p11 + q*4);

        // ---- prefetch W tile chunk + next tap's om (newer, still in flight) ----
        const short* wsrc = wstage + k*4096 + t*16;
        bf16x8 wv0 = *reinterpret_cast<const bf16x8*>(wsrc);
        bf16x8 wv1 = *reinterpret_cast<const bf16x8*>(wsrc + 8);
        int kn = (k < 8) ? k + 1 : 8;
        float dyn = omp[2*kn], dxn = omp[2*kn + 1], mzn = omp[18 + kn];

        // ---- combine + cvt ----
        bf16x8 us0, us1;
#pragma unroll
        for (int q = 0; q < 4; q++) {
#pragma unroll
            for (int j = 0; j < 4; j++) {
                float v = w00*ga[q][j] + w01*gb[q][j] + w10*gc[q][j] + w11*gd[q][j];
                short s = f2bf_s(v);
                if (q < 2) us0[q*4 + j] = s; else us1[(q-2)*4 + j] = s;
            }
        }

        __syncthreads();                                    // prev MFMA reads done
        *reinterpret_cast<bf16x8*>((char*)As + pxl*128 + ((cb     ) ^ ((pxl&7)<<4))) = us0;
        *reinterpret_cast<bf16x8*>((char*)As + pxl*128 + ((cb + 16) ^ ((pxl&7)<<4))) = us1;
        *reinterpret_cast<bf16x8*>((char*)Ws + t*32)      = wv0;
        *reinterpret_cast<bf16x8*>((char*)Ws + t*32 + 16) = wv1;
        __syncthreads();

#pragma unroll
        for (int s = 0; s < 2; s++) {
            const int bc = (s*64 + fq*16) ^ swz;
            bf16x8 a = *reinterpret_cast<const bf16x8*>((char*)As + (wv*16 + fr)*128 + bc);
#pragma unroll
            for (int j = 0; j < 4; j++) {
                bf16x8 bj = *reinterpret_cast<const bf16x8*>((char*)Ws + (j*16 + fr)*128 + bc);
                acc[j] = __builtin_amdgcn_mfma_f32_16x16x32_bf16(a, bj, acc[j], 0, 0, 0);
            }
        }
        dy = dyn; dx = dxn; mz = mzn;
    }

    // ---- epilogue: row px = wv*16 + fq*4 + reg, col o = j*16 + fr ----
    const int bo = px0 / HW_, po = px0 % HW_;
#pragma unroll
    for (int j = 0; j < 4; j++) {
        int o = j*16 + fr;
        float bv = bias[o];
        f4 r = { acc[j][0] + bv, acc[j][1] + bv, acc[j][2] + bv, acc[j][3] + bv };
        *reinterpret_cast<f4*>(&out[((size_t)(bo*64 + o))*HW_ + po + wv*16 + fq*4]) = r;
    }
}

// ---------------------------------------------------------------------------
extern "C" void kernel_launch(void* const* d_in, const int* in_sizes, int n_in,
                              void* d_out, int out_size, void* d_ws, size_t ws_size,
                              hipStream_t stream)
{
    const float* x   = (const float*)d_in[0];
    const float* wt  = (const float*)d_in[1];
    const float* bs  = (const float*)d_in[2];
    const float* cmw = (const float*)d_in[3];
    const float* cmb = (const float*)d_in[4];
    float* out = (float*)d_out;

    float* xs     = (float*)d_ws;                           // NPIX_*72 f32
    float* om     = xs + (size_t)NPIX_ * XC_;               // NPIX_*28 f32
    short* wstage = (short*)(om + (size_t)NPIX_ * OMC_);    // 9*4096 bf16
    short* cwB    = wstage + 9*4096;                        // 21*32*32 bf16

    prep_kernel <<<228, 256, 0, stream>>>(wt, cmw, wstage, cwB);
    xpose_kernel<<<NPIX_/128, 128, 0, stream>>>(x, xs);
    sim_kernel  <<<NPIX_/128, 256, 0, stream>>>(xs);
    cm_kernel   <<<NPIX_/64,  256, 0, stream>>>(xs, cwB, cmb, om);
    dcn_kernel  <<<NPIX_/64,  256, 0, stream>>>(xs, om, wstage, bs, out);
}